// Round 8
// baseline (185.907 us; speedup 1.0000x reference)
//
#include <hip/hip_runtime.h>
#include <hip/hip_bf16.h>
#include <math.h>

typedef __hip_bfloat16 bf16;
typedef short bf16x8 __attribute__((ext_vector_type(8)));   // 8 bf16 raw (4 VGPRs)
typedef float f32x4 __attribute__((ext_vector_type(4)));
typedef float f32x2 __attribute__((ext_vector_type(2)));

union alignas(16) Pack8 { bf16 h[8]; bf16x8 v; };

// native base-2 transcendentals (v_exp_f32 / v_log_f32 / v_rcp_f32)
#define EXP2F(x) __builtin_amdgcn_exp2f(x)
#define LOG2F(x) __builtin_amdgcn_logf(x)
#define RCPF(x)  __builtin_amdgcn_rcpf(x)

// Mean-table box: for scores in [TAB_LO, TAB_HI] (a,b in [0.533,1.502]),
// pc >= 0.596 always (corner-verified; pc unimodal in each var), so the
// output is ALWAYS the continuous mean there -> bilinear table lookup.
#define TAB_N   64
#define TAB_LO  (-0.35f)
#define TAB_HI  (1.25f)
#define TAB_STRIDE 65          // f32x2 pairs (T[ib],T[ib+1]), row stride 65

// ---------------------------------------------------------------------------
// f32 mean (Stirling shift-4, R0/R1-validated; err ~3e-5). Table gen only.
// ---------------------------------------------------------------------------
__device__ __forceinline__ float stirl2s(float z) {
    float iz = 1.f / z;
    return (z - 0.5f) * LOG2F(z) - 1.44269504f * z + 1.32574806f
         + iz * (0.12022651f - 0.00400749f * iz * iz);
}
__device__ __forceinline__ float sp4s(float x) {   // x(x+1)(x+2)(x+3)
    return (x * (x + 1.f)) * ((x + 2.f) * (x + 3.f));
}
__device__ float mean_f32(float sa, float sb) {
    float lw = LOG2F(1.f + EXP2F(sa * 1.44269504f));
    float lv = LOG2F(1.f + EXP2F(sb * 1.44269504f));
    lw = fminf(fmaxf(lw, 0.01442695f), 144.269504f);
    lv = fminf(fmaxf(lv, 0.01442695f), 144.269504f);
    float b = 0.69314718f * lv;
    float g = 1.44269504f / lw + 1.f;
    float gb = g + b;
    float lb2 = stirl2s(g + 4.f) + stirl2s(b + 4.f) - stirl2s(gb + 4.f)
              + LOG2F(sp4s(gb) / (sp4s(g) * sp4s(b)));
    float mean = fmaf(1.2f * b, EXP2F(lb2), -0.1f);
    return fminf(fmaxf(mean, 0.f), 1.f);
}

// ---------------------------------------------------------------------------
// Weight transposes f32 -> bf16 AND mean-table generation in ONE dispatch.
// ---------------------------------------------------------------------------
__global__ void prep_weights(const float* __restrict__ Wa1, const float* __restrict__ Wa2,
                             const float* __restrict__ Wb1, const float* __restrict__ Wb2,
                             bf16* __restrict__ oa1, bf16* __restrict__ oa2,
                             bf16* __restrict__ ob1, bf16* __restrict__ ob2,
                             float* __restrict__ tab) {
    if (blockIdx.x >= 1536) {
        int idx = (blockIdx.x - 1536) * 256 + threadIdx.x;
        if (idx >= TAB_N * TAB_N) return;
        int ia = idx >> 6, ib = idx & 63;
        const float step = (TAB_HI - TAB_LO) / (TAB_N - 1);
        float sa  = TAB_LO + ia * step;
        float sb  = TAB_LO + ib * step;
        int ib1 = ib < TAB_N - 1 ? ib + 1 : ib;
        float sb1 = TAB_LO + ib1 * step;
        tab[(ia * TAB_STRIDE + ib) * 2]     = mean_f32(sa, sb);
        tab[(ia * TAB_STRIDE + ib) * 2 + 1] = mean_f32(sa, sb1);
        return;
    }
    int idx = blockIdx.x * 256 + threadIdx.x;   // covers 393216
    if (idx < 131072) {
        int n = idx >> 9, k = idx & 511;
        oa1[idx] = __float2bfloat16(Wa1[k * 256 + n]);
    } else if (idx < 196608) {
        int i = idx - 131072; int n = i >> 8, k = i & 255;
        oa2[i] = __float2bfloat16(Wa2[k * 256 + n]);
    } else if (idx < 327680) {
        int i = idx - 196608; int n = i >> 9, k = i & 511;
        ob1[i] = __float2bfloat16(Wb1[k * 256 + n]);
    } else {
        int i = idx - 327680; int n = i >> 8, k = i & 255;
        ob2[i] = __float2bfloat16(Wb2[k * 256 + n]);
    }
}

// ---------------------------------------------------------------------------
// Fused 2-layer MLP — R7 algorithm (512 threads, 8 waves of 64x32) with LDS
// ALIASING: lA (layer-1 loop only) shares storage with lH (written only after
// that loop). 54272 B -> 3 blocks/CU (24 waves/CU, was 2/16).
// grid (128,1,4): z = {q@a, k@a, q@b, k@b}.
// ---------------------------------------------------------------------------
__global__ __launch_bounds__(512, 4)
void mlp_fused(const float* __restrict__ q, const float* __restrict__ k,
               const bf16* __restrict__ Wa1t, const bf16* __restrict__ Wa2t,
               const bf16* __restrict__ Wb1t, const bf16* __restrict__ Wb2t,
               bf16* __restrict__ qa, bf16* __restrict__ ka,
               bf16* __restrict__ qb, bf16* __restrict__ kb) {
    const int z = blockIdx.z;
    const float* X  = (z & 1) ? k : q;
    const bf16*  W1 = (z >> 1) ? Wb1t : Wa1t;
    const bf16*  W2 = (z >> 1) ? Wb2t : Wa2t;
    bf16* Y = (z == 0) ? qa : (z == 1) ? ka : (z == 2) ? qb : kb;
    const int m0 = blockIdx.x * 64;

    // [0,20480): lB (W staging, both layers)
    // [20480,54272): lH (64x264 bf16)  —  lA (64x40) ALIASES its head
    __shared__ alignas(16) char smem[54272];
    short* lB = (short*)smem;
    short* lH = (short*)(smem + 20480);
    short* lA = (short*)(smem + 20480);    // dead before lH is written

    const int tid  = threadIdx.x;
    const int wave = tid >> 6, lane = tid & 63;
    const int wn = wave * 32;                   // 8 waves x 32 cols = 256
    const int quad = lane >> 4, r16 = lane & 15;

    // ---- layer 1: K = 512, X is f32 (convert during staging)
    {
        f32x4 acc[4][2] = {};
        for (int kk = 0; kk < 512; kk += 32) {
            if (tid < 256) {
                int r = tid >> 2, c = (tid & 3) * 8;
                const float* p = X + (size_t)(m0 + r) * 512 + kk + c;
                Pack8 u;
#pragma unroll
                for (int j = 0; j < 8; j++) u.h[j] = __float2bfloat16(p[j]);
                *(bf16x8*)&lA[r * 40 + c] = u.v;
            }
            for (int i = tid; i < 1024; i += 512) {
                int r = i >> 2, c = (i & 3) * 8;
                *(bf16x8*)&lB[r * 40 + c] =
                    *(const bf16x8*)(W1 + (size_t)r * 512 + kk + c);
            }
            __syncthreads();
            bf16x8 af[4], bfr[2];
#pragma unroll
            for (int f = 0; f < 4; f++)
                af[f] = *(const bf16x8*)&lA[(f * 16 + r16) * 40 + quad * 8];
#pragma unroll
            for (int f = 0; f < 2; f++)
                bfr[f] = *(const bf16x8*)&lB[(wn + f * 16 + r16) * 40 + quad * 8];
#pragma unroll
            for (int i = 0; i < 4; i++)
#pragma unroll
                for (int j = 0; j < 2; j++)
                    acc[i][j] = __builtin_amdgcn_mfma_f32_16x16x32_bf16(
                        af[i], bfr[j], acc[i][j], 0, 0, 0);
            __syncthreads();
        }
        // lA is dead from here; lH takes over the aliased region
#pragma unroll
        for (int i = 0; i < 4; i++)
#pragma unroll
            for (int j = 0; j < 2; j++)
#pragma unroll
                for (int r = 0; r < 4; r++) {
                    float v = acc[i][j][r];
                    v = v > 0.f ? v : 0.f;
                    ((bf16*)lH)[(i * 16 + quad * 4 + r) * 264 + wn + j * 16 + r16] =
                        __float2bfloat16(v);
                }
    }
    __syncthreads();

    // ---- layer 2: K = 256, A comes from lH
    f32x4 acc2[4][2] = {};
    for (int kk = 0; kk < 256; kk += 32) {
        for (int i = tid; i < 1024; i += 512) {
            int r = i >> 2, c = (i & 3) * 8;
            *(bf16x8*)&lB[r * 40 + c] =
                *(const bf16x8*)(W2 + (size_t)r * 256 + kk + c);
        }
        __syncthreads();
        bf16x8 af[4], bfr[2];
#pragma unroll
        for (int f = 0; f < 4; f++)
            af[f] = *(const bf16x8*)&lH[(f * 16 + r16) * 264 + kk + quad * 8];
#pragma unroll
        for (int f = 0; f < 2; f++)
            bfr[f] = *(const bf16x8*)&lB[(wn + f * 16 + r16) * 40 + quad * 8];
#pragma unroll
        for (int i = 0; i < 4; i++)
#pragma unroll
            for (int j = 0; j < 2; j++)
                acc2[i][j] = __builtin_amdgcn_mfma_f32_16x16x32_bf16(
                    af[i], bfr[j], acc2[i][j], 0, 0, 0);
        __syncthreads();
    }

#pragma unroll
    for (int i = 0; i < 4; i++) {
        int rbase = m0 + i * 16 + quad * 4;
#pragma unroll
        for (int j = 0; j < 2; j++) {
            int col = wn + j * 16 + r16;
#pragma unroll
            for (int r = 0; r < 4; r++) {
                float v = acc2[i][j][r];
                v = v > 0.f ? v : 0.f;
                Y[(size_t)(rbase + r) * 256 + col] = __float2bfloat16(v);
            }
        }
    }
}

// ---------------------------------------------------------------------------
// Packed f32x2 helpers.
// ---------------------------------------------------------------------------
__device__ __forceinline__ f32x2 vexp2(f32x2 x) {
    f32x2 r; r.x = EXP2F(x.x); r.y = EXP2F(x.y); return r;
}
__device__ __forceinline__ f32x2 vlog2(f32x2 x) {
    f32x2 r; r.x = LOG2F(x.x); r.y = LOG2F(x.y); return r;
}
__device__ __forceinline__ f32x2 vrcp(f32x2 x) {
    f32x2 r; r.x = RCPF(x.x); r.y = RCPF(x.y); return r;
}
__device__ __forceinline__ f32x2 vclamp(f32x2 x, float lo, float hi) {
    f32x2 r;
    r.x = fminf(fmaxf(x.x, lo), hi);
    r.y = fminf(fmaxf(x.y, lo), hi);
    return r;
}

// Exact HardKuma pair (round-1 validated). COLD fallback path only.
__device__ __noinline__ f32x2 hardkuma_slow(f32x2 la, f32x2 lb) {
    const float LOG2E = 1.44269504f;
    f32x2 lw = vlog2(1.f + vexp2(la * LOG2E));
    f32x2 lv = vlog2(1.f + vexp2(lb * LOG2E));
    lw = vclamp(lw, 0.01442695f, 144.269504f);   // a in [0.01,100]
    lv = vclamp(lv, 0.01442695f, 144.269504f);
    f32x2 b = 0.69314718f * lv;

    f32x2 t0a = vexp2(-2.48490665f * lw);        // 12^{-a}
    f32x2 t1a = vexp2(-0.08701138f * lw);        // (12/11)^{-a}
    f32x2 q0 = vexp2(b * vlog2(1.f - t0a));      // 1 - p0
    f32x2 p1 = vexp2(b * vlog2(1.f - t1a));      // P(h=1)
    f32x2 pc = q0 - p1;
    f32x2 p0 = 1.f - q0;

    f32x2 g  = 1.44269504f * vrcp(lw) + 1.f;
    f32x2 gb = g + b;
    f32x2 g2 = g + 2.f, b2 = b + 2.f, gb2 = gb + 2.f;

    f32x2 s = (g + 1.5f) * vlog2(g2) + (b + 1.5f) * vlog2(b2)
            - (gb + 1.5f) * vlog2(gb2);

    const float C1 = 0.12022459f;                // log2e/12
    const float C2 = -0.00400749f;               // -log2e/360
    f32x2 pg  = g2 * b2;
    f32x2 rr3 = vrcp(pg * gb2);
    f32x2 ig  = rr3 * (b2 * gb2);
    f32x2 ib  = rr3 * (g2 * gb2);
    f32x2 igb = rr3 * pg;
    f32x2 corr = ig  * (C1 + C2 * (ig  * ig))
               + ib  * (C1 + C2 * (ib  * ib))
               - igb * (C1 + C2 * (igb * igb));
    s += corr - 1.55964202f;                     // 0.5*log2(2pi) - 2*log2e

    f32x2 ng = g * (g + 1.f), nb = b * (b + 1.f), ngb = gb * (gb + 1.f);
    s += vlog2(ngb * vrcp(ng * nb));

    f32x2 mean = (1.2f * b) * vexp2(s) - 0.1f;
    mean = vclamp(mean, 0.f, 1.f);

    f32x2 att;
    att.x = (pc.x < 0.5f) ? ((p0.x > p1.x) ? 0.f : 1.f) : mean.x;
    att.y = (pc.y < 0.5f) ? ((p0.y > p1.y) ? 0.f : 1.f) : mean.y;
    return att;
}

// ---------------------------------------------------------------------------
// Fused score GEMMs + table-lookup HardKuma epilogue — R7 algorithm (512
// threads, 8 waves of 64x32) with LDS ALIASING: the 33 KB mean table is
// loaded into the (dead) K-loop tile region at epilogue start. LDS drops
// 74.75 -> 41 KB -> 3 blocks/CU (24 waves/CU, was 2/16): one block's
// epilogue VALU/gathers overlaps another's staging/MFMA. grid (16,16,4).
// ---------------------------------------------------------------------------
__global__ __launch_bounds__(512, 4)
void kuma_attn(const bf16* __restrict__ qa, const bf16* __restrict__ ka,
               const bf16* __restrict__ qb, const bf16* __restrict__ kb,
               const float* __restrict__ dist_emb, const float* __restrict__ tabg,
               float* __restrict__ out) {
    const int bidx = blockIdx.z;
    const int t0 = blockIdx.x * 128;
    const int s0 = blockIdx.y * 128;

    // [0,10240) lQa | [10240,20480) lQb | [20480,30720) lKa | [30720,40960) lKb
    // epilogue: sTab (33280 B) aliases [0,33280)
    // [40960,41052): sDist
    __shared__ alignas(16) char smem[41052];
    short* lQa = (short*)smem;
    short* lQb = (short*)(smem + 10240);
    short* lKa = (short*)(smem + 20480);
    short* lKb = (short*)(smem + 30720);
    float* sTab  = (float*)smem;
    float* sDist = (float*)(smem + 40960);

    const int tid = threadIdx.x;
    if (tid < 23) sDist[tid] = dist_emb[tid];

    const int wave = tid >> 6, lane = tid & 63;
    const int wm = (wave >> 2) * 64;             // 2 wave-rows of 64
    const int wn = (wave & 3) * 32;              // 4 wave-cols of 32
    const int quad = lane >> 4, r16 = lane & 15;
    const size_t base = (size_t)bidx * 2048 * 256;

    f32x4 accA[4][2] = {};
    f32x4 accB[4][2] = {};

    const int r0 = tid >> 2, c0 = (tid & 3) * 8;    // rows 0..127, one pass

    for (int kk = 0; kk < 256; kk += 32) {
        {
            size_t gq = base + (size_t)(t0 + r0) * 256 + kk + c0;
            size_t gk = base + (size_t)(s0 + r0) * 256 + kk + c0;
            *(bf16x8*)&lQa[r0 * 40 + c0] = *(const bf16x8*)(qa + gq);
            *(bf16x8*)&lQb[r0 * 40 + c0] = *(const bf16x8*)(qb + gq);
            *(bf16x8*)&lKa[r0 * 40 + c0] = *(const bf16x8*)(ka + gk);
            *(bf16x8*)&lKb[r0 * 40 + c0] = *(const bf16x8*)(kb + gk);
        }
        __syncthreads();
        bf16x8 aA[4], aB[4], bA[2], bB[2];
#pragma unroll
        for (int f = 0; f < 4; f++) {
            int ar = (wm + f * 16 + r16) * 40 + quad * 8;
            aA[f] = *(const bf16x8*)&lQa[ar];
            aB[f] = *(const bf16x8*)&lQb[ar];
        }
#pragma unroll
        for (int f = 0; f < 2; f++) {
            int br = (wn + f * 16 + r16) * 40 + quad * 8;
            bA[f] = *(const bf16x8*)&lKa[br];
            bB[f] = *(const bf16x8*)&lKb[br];
        }
#pragma unroll
        for (int i = 0; i < 4; i++)
#pragma unroll
            for (int j = 0; j < 2; j++) {
                accA[i][j] = __builtin_amdgcn_mfma_f32_16x16x32_bf16(
                    aA[i], bA[j], accA[i][j], 0, 0, 0);
                accB[i][j] = __builtin_amdgcn_mfma_f32_16x16x32_bf16(
                    aB[i], bB[j], accB[i][j], 0, 0, 0);
            }
        __syncthreads();
    }

    // Load the mean table into the now-dead tile region, then sync once.
    for (int i = tid; i < (TAB_N * TAB_STRIDE * 2) / 4; i += 512)
        ((f32x4*)sTab)[i] = ((const f32x4*)tabg)[i];
    __syncthreads();

    // Epilogue: bilinear mean-table lookup (pairs via ds_read_b64);
    // __any-guarded exact fallback for out-of-box lanes.
    const float SCALE = (TAB_N - 1) / (TAB_HI - TAB_LO);   // 39.375
#pragma unroll
    for (int i = 0; i < 4; i++) {
#pragma unroll
        for (int j = 0; j < 2; j++) {
            int s = s0 + wn + j * 16 + r16;
#pragma unroll
            for (int rr = 0; rr < 2; rr++) {
                int t = t0 + wm + i * 16 + quad * 4 + rr * 2;
                int d0 = s - t;
                int d1 = d0 - 1;
                d0 = d0 < -11 ? -11 : (d0 > 11 ? 11 : d0);
                d1 = d1 < -11 ? -11 : (d1 > 11 ? 11 : d1);
                float rd0 = sDist[d0 + 11];
                float rd1 = sDist[d1 + 11];
                f32x2 la  = { accA[i][j][rr * 2] + rd0, accA[i][j][rr * 2 + 1] + rd1 };
                f32x2 lbv = { accB[i][j][rr * 2] + rd0, accB[i][j][rr * 2 + 1] + rd1 };

                float mn = fminf(fminf(la.x, la.y), fminf(lbv.x, lbv.y));
                float mx = fmaxf(fmaxf(la.x, la.y), fmaxf(lbv.x, lbv.y));

                f32x2 u = vclamp((la  - TAB_LO) * SCALE, 0.f, (float)(TAB_N - 1));
                f32x2 v = vclamp((lbv - TAB_LO) * SCALE, 0.f, (float)(TAB_N - 1));
                int ia0 = (int)u.x; ia0 = ia0 > TAB_N - 2 ? TAB_N - 2 : ia0;
                int ia1 = (int)u.y; ia1 = ia1 > TAB_N - 2 ? TAB_N - 2 : ia1;
                int ib0 = (int)v.x; ib0 = ib0 > TAB_N - 2 ? TAB_N - 2 : ib0;
                int ib1 = (int)v.y; ib1 = ib1 > TAB_N - 2 ? TAB_N - 2 : ib1;
                f32x2 fa = { u.x - (float)ia0, u.y - (float)ia1 };
                f32x2 fb = { v.x - (float)ib0, v.y - (float)ib1 };
                int o0 = (ia0 * TAB_STRIDE + ib0) * 2;
                int o1 = (ia1 * TAB_STRIDE + ib1) * 2;
                f32x2 e0r0 = *(const f32x2*)&sTab[o0];
                f32x2 e0r1 = *(const f32x2*)&sTab[o0 + TAB_STRIDE * 2];
                f32x2 e1r0 = *(const f32x2*)&sTab[o1];
                f32x2 e1r1 = *(const f32x2*)&sTab[o1 + TAB_STRIDE * 2];
                f32x2 m0 = { e0r0.x + fb.x * (e0r0.y - e0r0.x),
                             e1r0.x + fb.y * (e1r0.y - e1r0.x) };
                f32x2 m1 = { e0r1.x + fb.x * (e0r1.y - e0r1.x),
                             e1r1.x + fb.y * (e1r1.y - e1r1.x) };
                f32x2 att = m0 + fa * (m1 - m0);

                bool oob = (mn < TAB_LO) | (mx > TAB_HI);
                if (__builtin_expect(__any(oob), 0)) {
                    f32x2 ex = hardkuma_slow(la, lbv);
                    if (oob) att = ex;
                }

                out[((size_t)bidx * 2048 + t) * 2048 + s] = att.x;
                out[((size_t)bidx * 2048 + t + 1) * 2048 + s] = att.y;
            }
        }
    }
}

// ---------------------------------------------------------------------------
extern "C" void kernel_launch(void* const* d_in, const int* in_sizes, int n_in,
                              void* d_out, int out_size, void* d_ws, size_t ws_size,
                              hipStream_t stream) {
    const float* q    = (const float*)d_in[0];
    const float* k    = (const float*)d_in[1];
    const float* Wa1  = (const float*)d_in[2];
    const float* Wa2  = (const float*)d_in[4];
    const float* Wb1  = (const float*)d_in[6];
    const float* Wb2  = (const float*)d_in[8];
    const float* dist = (const float*)d_in[10];
    float* out = (float*)d_out;

    bf16* wsbf = (bf16*)d_ws;
    bf16* Wa1t = wsbf;                 // 512*256
    bf16* Wa2t = Wa1t + 131072;        // 256*256
    bf16* Wb1t = Wa2t + 65536;
    bf16* Wb2t = Wb1t + 131072;
    bf16* qa   = Wb2t + 65536;         // 8192*256 each
    bf16* ka   = qa + 2097152;
    bf16* qb   = ka + 2097152;
    bf16* kb   = qb + 2097152;
    bf16* tail = kb + 2097152;
    float* tabg = (float*)tail;        // 64*65*2 f32 = 33.3 KB

    // prep (blocks 0..1535) + table gen (blocks 1536..1551), one launch
    prep_weights<<<1552, 256, 0, stream>>>(Wa1, Wa2, Wb1, Wb2,
                                           Wa1t, Wa2t, Wb1t, Wb2t, tabg);

    dim3 g1(128, 1, 4), blk512(512, 1, 1);
    mlp_fused<<<g1, blk512, 0, stream>>>(q, k, Wa1t, Wa2t, Wb1t, Wb2t,
                                         qa, ka, qb, kb);

    dim3 g2(16, 16, 4);
    kuma_attn<<<g2, blk512, 0, stream>>>(qa, ka, qb, kb, dist, tabg, out);
}

// Round 9
// 180.656 us; speedup vs baseline: 1.0291x; 1.0291x over previous
//
#include <hip/hip_runtime.h>
#include <hip/hip_bf16.h>
#include <math.h>

typedef __hip_bfloat16 bf16;
typedef short bf16x8 __attribute__((ext_vector_type(8)));   // 8 bf16 raw (4 VGPRs)
typedef float f32x4 __attribute__((ext_vector_type(4)));
typedef float f32x2 __attribute__((ext_vector_type(2)));

union alignas(16) Pack8 { bf16 h[8]; bf16x8 v; };

// native base-2 transcendentals (v_exp_f32 / v_log_f32 / v_rcp_f32)
#define EXP2F(x) __builtin_amdgcn_exp2f(x)
#define LOG2F(x) __builtin_amdgcn_logf(x)
#define RCPF(x)  __builtin_amdgcn_rcpf(x)

// async global->LDS DMA, 16 B/lane. Dest must be the WAVE-UNIFORM base; HW
// scatters lane l to base + l*16 (guide §5 / m97/m104). Size must be literal.
__device__ __forceinline__ void gload16(const void* g, void* l) {
    __builtin_amdgcn_global_load_lds(
        (const __attribute__((address_space(1))) void*)g,
        (__attribute__((address_space(3))) void*)l, 16, 0, 0);
}

// Mean-table box: for scores in [TAB_LO, TAB_HI] (a,b in [0.533,1.502]),
// pc >= 0.596 always (corner-verified; pc unimodal in each var), so the
// output is ALWAYS the continuous mean there -> bilinear table lookup.
#define TAB_N   64
#define TAB_LO  (-0.35f)
#define TAB_HI  (1.25f)
#define TAB_STRIDE 65          // f32x2 pairs (T[ib],T[ib+1]), row stride 65

// ---------------------------------------------------------------------------
// f32 mean (Stirling shift-4, R0/R1-validated; err ~3e-5). Table gen only.
// ---------------------------------------------------------------------------
__device__ __forceinline__ float stirl2s(float z) {
    float iz = 1.f / z;
    return (z - 0.5f) * LOG2F(z) - 1.44269504f * z + 1.32574806f
         + iz * (0.12022651f - 0.00400749f * iz * iz);
}
__device__ __forceinline__ float sp4s(float x) {   // x(x+1)(x+2)(x+3)
    return (x * (x + 1.f)) * ((x + 2.f) * (x + 3.f));
}
__device__ float mean_f32(float sa, float sb) {
    float lw = LOG2F(1.f + EXP2F(sa * 1.44269504f));
    float lv = LOG2F(1.f + EXP2F(sb * 1.44269504f));
    lw = fminf(fmaxf(lw, 0.01442695f), 144.269504f);
    lv = fminf(fmaxf(lv, 0.01442695f), 144.269504f);
    float b = 0.69314718f * lv;
    float g = 1.44269504f / lw + 1.f;
    float gb = g + b;
    float lb2 = stirl2s(g + 4.f) + stirl2s(b + 4.f) - stirl2s(gb + 4.f)
              + LOG2F(sp4s(gb) / (sp4s(g) * sp4s(b)));
    float mean = fmaf(1.2f * b, EXP2F(lb2), -0.1f);
    return fminf(fmaxf(mean, 0.f), 1.f);
}

// ---------------------------------------------------------------------------
// Weight transposes f32 -> bf16 AND mean-table generation in ONE dispatch.
// ---------------------------------------------------------------------------
__global__ void prep_weights(const float* __restrict__ Wa1, const float* __restrict__ Wa2,
                             const float* __restrict__ Wb1, const float* __restrict__ Wb2,
                             bf16* __restrict__ oa1, bf16* __restrict__ oa2,
                             bf16* __restrict__ ob1, bf16* __restrict__ ob2,
                             float* __restrict__ tab) {
    if (blockIdx.x >= 1536) {
        int idx = (blockIdx.x - 1536) * 256 + threadIdx.x;
        if (idx >= TAB_N * TAB_N) return;
        int ia = idx >> 6, ib = idx & 63;
        const float step = (TAB_HI - TAB_LO) / (TAB_N - 1);
        float sa  = TAB_LO + ia * step;
        float sb  = TAB_LO + ib * step;
        int ib1 = ib < TAB_N - 1 ? ib + 1 : ib;
        float sb1 = TAB_LO + ib1 * step;
        tab[(ia * TAB_STRIDE + ib) * 2]     = mean_f32(sa, sb);
        tab[(ia * TAB_STRIDE + ib) * 2 + 1] = mean_f32(sa, sb1);
        return;
    }
    int idx = blockIdx.x * 256 + threadIdx.x;   // covers 393216
    if (idx < 131072) {
        int n = idx >> 9, k = idx & 511;
        oa1[idx] = __float2bfloat16(Wa1[k * 256 + n]);
    } else if (idx < 196608) {
        int i = idx - 131072; int n = i >> 8, k = i & 255;
        oa2[i] = __float2bfloat16(Wa2[k * 256 + n]);
    } else if (idx < 327680) {
        int i = idx - 196608; int n = i >> 9, k = i & 511;
        ob1[i] = __float2bfloat16(Wb1[k * 256 + n]);
    } else {
        int i = idx - 327680; int n = i >> 8, k = i & 255;
        ob2[i] = __float2bfloat16(Wb2[k * 256 + n]);
    }
}

// ---------------------------------------------------------------------------
// Fused 2-layer MLP — 512 threads (8 waves of 64x32), BK=64, W tiles staged
// via global_load_lds DMA into unpadded [256][64] (no wave-issued ds_writes,
// no staging VGPRs). X tile reg-staged (needs f32->bf16 cvt) into unpadded
// [64][64]. Barriers halve vs R7. grid (128,1,4): z = {q@a, k@a, q@b, k@b}.
// ---------------------------------------------------------------------------
__global__ __launch_bounds__(512, 4)
void mlp_fused(const float* __restrict__ q, const float* __restrict__ k,
               const bf16* __restrict__ Wa1t, const bf16* __restrict__ Wa2t,
               const bf16* __restrict__ Wb1t, const bf16* __restrict__ Wb2t,
               bf16* __restrict__ qa, bf16* __restrict__ ka,
               bf16* __restrict__ qb, bf16* __restrict__ kb) {
    const int z = blockIdx.z;
    const float* X  = (z & 1) ? k : q;
    const bf16*  W1 = (z >> 1) ? Wb1t : Wa1t;
    const bf16*  W2 = (z >> 1) ? Wb2t : Wa2t;
    bf16* Y = (z == 0) ? qa : (z == 1) ? ka : (z == 2) ? qb : kb;
    const int m0 = blockIdx.x * 64;

    // [0,32768): lB [256][64] bf16 (DMA-linear, unpadded)
    // [32768,66560): lH [64][264] bf16 — lA [64][64] ALIASES its head
    __shared__ alignas(16) char smem[66560];
    short* lB = (short*)smem;
    short* lH = (short*)(smem + 32768);
    short* lA = (short*)(smem + 32768);    // dead before lH is written

    const int tid  = threadIdx.x;
    const int wave = tid >> 6, lane = tid & 63;
    const int wn = wave * 32;                   // 8 waves x 32 cols = 256
    const int quad = lane >> 4, r16 = lane & 15;
    const int srow = lane >> 3, scol = (lane & 7) * 8;   // DMA lane mapping
    const int car = tid >> 3,  cac = (tid & 7) * 8;      // lA convert mapping

    // ---- layer 1: K = 512, BK = 64 (8 iters)
    {
        f32x4 acc[4][2] = {};
        for (int kk = 0; kk < 512; kk += 64) {
            {   // X convert-stage: all 512 threads, 8 elems each
                const float* p = X + (size_t)(m0 + car) * 512 + kk + cac;
                Pack8 u;
#pragma unroll
                for (int j = 0; j < 8; j++) u.h[j] = __float2bfloat16(p[j]);
                *(bf16x8*)&lA[car * 64 + cac] = u.v;
            }
#pragma unroll
            for (int j = 0; j < 4; j++) {       // W1 rows via DMA, 4/wave
                int row = wave * 32 + j * 8 + srow;
                gload16(W1 + (size_t)row * 512 + kk + scol,
                        lB + (wave * 32 + j * 8) * 64);
            }
            __syncthreads();
#pragma unroll
            for (int ks = 0; ks < 2; ks++) {
                int co = ks * 32 + quad * 8;
                bf16x8 af[4], bfr[2];
#pragma unroll
                for (int f = 0; f < 4; f++)
                    af[f] = *(const bf16x8*)&lA[(f * 16 + r16) * 64 + co];
#pragma unroll
                for (int f = 0; f < 2; f++)
                    bfr[f] = *(const bf16x8*)&lB[(wn + f * 16 + r16) * 64 + co];
#pragma unroll
                for (int i = 0; i < 4; i++)
#pragma unroll
                    for (int j = 0; j < 2; j++)
                        acc[i][j] = __builtin_amdgcn_mfma_f32_16x16x32_bf16(
                            af[i], bfr[j], acc[i][j], 0, 0, 0);
            }
            __syncthreads();
        }
        // lA dead; lH takes over the aliased region
#pragma unroll
        for (int i = 0; i < 4; i++)
#pragma unroll
            for (int j = 0; j < 2; j++)
#pragma unroll
                for (int r = 0; r < 4; r++) {
                    float v = acc[i][j][r];
                    v = v > 0.f ? v : 0.f;
                    ((bf16*)lH)[(i * 16 + quad * 4 + r) * 264 + wn + j * 16 + r16] =
                        __float2bfloat16(v);
                }
    }
    __syncthreads();

    // ---- layer 2: K = 256, BK = 64 (4 iters), A from lH, W2 via DMA
    f32x4 acc2[4][2] = {};
    for (int kk = 0; kk < 256; kk += 64) {
#pragma unroll
        for (int j = 0; j < 4; j++) {
            int row = wave * 32 + j * 8 + srow;
            gload16(W2 + (size_t)row * 256 + kk + scol,
                    lB + (wave * 32 + j * 8) * 64);
        }
        __syncthreads();
#pragma unroll
        for (int ks = 0; ks < 2; ks++) {
            int co = kk + ks * 32 + quad * 8;
            bf16x8 af[4], bfr[2];
#pragma unroll
            for (int f = 0; f < 4; f++)
                af[f] = *(const bf16x8*)&lH[(f * 16 + r16) * 264 + co];
#pragma unroll
            for (int f = 0; f < 2; f++)
                bfr[f] = *(const bf16x8*)&lB[(wn + f * 16 + r16) * 64 + ks * 32 + quad * 8];
#pragma unroll
            for (int i = 0; i < 4; i++)
#pragma unroll
                for (int j = 0; j < 2; j++)
                    acc2[i][j] = __builtin_amdgcn_mfma_f32_16x16x32_bf16(
                        af[i], bfr[j], acc2[i][j], 0, 0, 0);
        }
        __syncthreads();
    }

#pragma unroll
    for (int i = 0; i < 4; i++) {
        int rbase = m0 + i * 16 + quad * 4;
#pragma unroll
        for (int j = 0; j < 2; j++) {
            int col = wn + j * 16 + r16;
#pragma unroll
            for (int r = 0; r < 4; r++) {
                float v = acc2[i][j][r];
                v = v > 0.f ? v : 0.f;
                Y[(size_t)(rbase + r) * 256 + col] = __float2bfloat16(v);
            }
        }
    }
}

// ---------------------------------------------------------------------------
// Packed f32x2 helpers.
// ---------------------------------------------------------------------------
__device__ __forceinline__ f32x2 vexp2(f32x2 x) {
    f32x2 r; r.x = EXP2F(x.x); r.y = EXP2F(x.y); return r;
}
__device__ __forceinline__ f32x2 vlog2(f32x2 x) {
    f32x2 r; r.x = LOG2F(x.x); r.y = LOG2F(x.y); return r;
}
__device__ __forceinline__ f32x2 vrcp(f32x2 x) {
    f32x2 r; r.x = RCPF(x.x); r.y = RCPF(x.y); return r;
}
__device__ __forceinline__ f32x2 vclamp(f32x2 x, float lo, float hi) {
    f32x2 r;
    r.x = fminf(fmaxf(x.x, lo), hi);
    r.y = fminf(fmaxf(x.y, lo), hi);
    return r;
}

// Exact HardKuma pair (round-1 validated). COLD fallback path only.
__device__ __noinline__ f32x2 hardkuma_slow(f32x2 la, f32x2 lb) {
    const float LOG2E = 1.44269504f;
    f32x2 lw = vlog2(1.f + vexp2(la * LOG2E));
    f32x2 lv = vlog2(1.f + vexp2(lb * LOG2E));
    lw = vclamp(lw, 0.01442695f, 144.269504f);   // a in [0.01,100]
    lv = vclamp(lv, 0.01442695f, 144.269504f);
    f32x2 b = 0.69314718f * lv;

    f32x2 t0a = vexp2(-2.48490665f * lw);        // 12^{-a}
    f32x2 t1a = vexp2(-0.08701138f * lw);        // (12/11)^{-a}
    f32x2 q0 = vexp2(b * vlog2(1.f - t0a));      // 1 - p0
    f32x2 p1 = vexp2(b * vlog2(1.f - t1a));      // P(h=1)
    f32x2 pc = q0 - p1;
    f32x2 p0 = 1.f - q0;

    f32x2 g  = 1.44269504f * vrcp(lw) + 1.f;
    f32x2 gb = g + b;
    f32x2 g2 = g + 2.f, b2 = b + 2.f, gb2 = gb + 2.f;

    f32x2 s = (g + 1.5f) * vlog2(g2) + (b + 1.5f) * vlog2(b2)
            - (gb + 1.5f) * vlog2(gb2);

    const float C1 = 0.12022459f;                // log2e/12
    const float C2 = -0.00400749f;               // -log2e/360
    f32x2 pg  = g2 * b2;
    f32x2 rr3 = vrcp(pg * gb2);
    f32x2 ig  = rr3 * (b2 * gb2);
    f32x2 ib  = rr3 * (g2 * gb2);
    f32x2 igb = rr3 * pg;
    f32x2 corr = ig  * (C1 + C2 * (ig  * ig))
               + ib  * (C1 + C2 * (ib  * ib))
               - igb * (C1 + C2 * (igb * igb));
    s += corr - 1.55964202f;                     // 0.5*log2(2pi) - 2*log2e

    f32x2 ng = g * (g + 1.f), nb = b * (b + 1.f), ngb = gb * (gb + 1.f);
    s += vlog2(ngb * vrcp(ng * nb));

    f32x2 mean = (1.2f * b) * vexp2(s) - 0.1f;
    mean = vclamp(mean, 0.f, 1.f);

    f32x2 att;
    att.x = (pc.x < 0.5f) ? ((p0.x > p1.x) ? 0.f : 1.f) : mean.x;
    att.y = (pc.y < 0.5f) ? ((p0.y > p1.y) ? 0.f : 1.f) : mean.y;
    return att;
}

// ---------------------------------------------------------------------------
// Fused score GEMMs + table epilogue — 512 threads (8 waves of 64x32), BK=64,
// all four tiles staged via global_load_lds DMA into unpadded [128][64]
// (fragment reads: 2-way bank alias = free per m136; staging leaves the wave
// instruction stream entirely). Barriers 16 -> 8. Table aliases the dead
// tile region for the epilogue. grid (16,16,4).
// ---------------------------------------------------------------------------
__global__ __launch_bounds__(512, 4)
void kuma_attn(const bf16* __restrict__ qa, const bf16* __restrict__ ka,
               const bf16* __restrict__ qb, const bf16* __restrict__ kb,
               const float* __restrict__ dist_emb, const float* __restrict__ tabg,
               float* __restrict__ out) {
    const int bidx = blockIdx.z;
    const int t0 = blockIdx.x * 128;
    const int s0 = blockIdx.y * 128;

    // [0,16384) lQa | [16384,32768) lQb | [32768,49152) lKa | [49152,65536) lKb
    // epilogue: sTab (33280 B) aliases [0,33280);  sDist at [65536,65628)
    __shared__ alignas(16) char smem[65628];
    short* lQa = (short*)smem;
    short* lQb = (short*)(smem + 16384);
    short* lKa = (short*)(smem + 32768);
    short* lKb = (short*)(smem + 49152);
    float* sTab  = (float*)smem;
    float* sDist = (float*)(smem + 65536);

    const int tid = threadIdx.x;
    if (tid < 23) sDist[tid] = dist_emb[tid];

    const int wave = tid >> 6, lane = tid & 63;
    const int wm = (wave >> 2) * 64;             // 2 wave-rows of 64
    const int wn = (wave & 3) * 32;              // 4 wave-cols of 32
    const int quad = lane >> 4, r16 = lane & 15;
    const size_t base = (size_t)bidx * 2048 * 256;

    const int srow = lane >> 3, scol = (lane & 7) * 8;   // DMA lane mapping

    f32x4 accA[4][2] = {};
    f32x4 accB[4][2] = {};

    for (int kk = 0; kk < 256; kk += 64) {
#pragma unroll
        for (int j = 0; j < 2; j++) {            // 8 DMA per wave per iter
            int row = wave * 16 + j * 8 + srow;
            size_t gq = base + (size_t)(t0 + row) * 256 + kk + scol;
            size_t gk = base + (size_t)(s0 + row) * 256 + kk + scol;
            int ld = (wave * 16 + j * 8) * 64;   // shorts (wave-uniform)
            gload16(qa + gq, lQa + ld);
            gload16(qb + gq, lQb + ld);
            gload16(ka + gk, lKa + ld);
            gload16(kb + gk, lKb + ld);
        }
        __syncthreads();                          // drains DMA (vmcnt) + WAR
#pragma unroll
        for (int ks = 0; ks < 2; ks++) {
            int co = ks * 32 + quad * 8;
            bf16x8 aA[4], aB[4], bA[2], bB[2];
#pragma unroll
            for (int f = 0; f < 4; f++) {
                int ar = (wm + f * 16 + r16) * 64 + co;
                aA[f] = *(const bf16x8*)&lQa[ar];
                aB[f] = *(const bf16x8*)&lQb[ar];
            }
#pragma unroll
            for (int f = 0; f < 2; f++) {
                int br = (wn + f * 16 + r16) * 64 + co;
                bA[f] = *(const bf16x8*)&lKa[br];
                bB[f] = *(const bf16x8*)&lKb[br];
            }
#pragma unroll
            for (int i = 0; i < 4; i++)
#pragma unroll
                for (int j = 0; j < 2; j++) {
                    accA[i][j] = __builtin_amdgcn_mfma_f32_16x16x32_bf16(
                        aA[i], bA[j], accA[i][j], 0, 0, 0);
                    accB[i][j] = __builtin_amdgcn_mfma_f32_16x16x32_bf16(
                        aB[i], bB[j], accB[i][j], 0, 0, 0);
                }
        }
        __syncthreads();
    }

    // Load the mean table into the now-dead tile region, then sync once.
    for (int i = tid; i < (TAB_N * TAB_STRIDE * 2) / 4; i += 512)
        ((f32x4*)sTab)[i] = ((const f32x4*)tabg)[i];
    __syncthreads();

    // Epilogue: bilinear mean-table lookup (pairs via ds_read_b64);
    // __any-guarded exact fallback for out-of-box lanes.
    const float SCALE = (TAB_N - 1) / (TAB_HI - TAB_LO);   // 39.375
#pragma unroll
    for (int i = 0; i < 4; i++) {
#pragma unroll
        for (int j = 0; j < 2; j++) {
            int s = s0 + wn + j * 16 + r16;
#pragma unroll
            for (int rr = 0; rr < 2; rr++) {
                int t = t0 + wm + i * 16 + quad * 4 + rr * 2;
                int d0 = s - t;
                int d1 = d0 - 1;
                d0 = d0 < -11 ? -11 : (d0 > 11 ? 11 : d0);
                d1 = d1 < -11 ? -11 : (d1 > 11 ? 11 : d1);
                float rd0 = sDist[d0 + 11];
                float rd1 = sDist[d1 + 11];
                f32x2 la  = { accA[i][j][rr * 2] + rd0, accA[i][j][rr * 2 + 1] + rd1 };
                f32x2 lbv = { accB[i][j][rr * 2] + rd0, accB[i][j][rr * 2 + 1] + rd1 };

                float mn = fminf(fminf(la.x, la.y), fminf(lbv.x, lbv.y));
                float mx = fmaxf(fmaxf(la.x, la.y), fmaxf(lbv.x, lbv.y));

                f32x2 u = vclamp((la  - TAB_LO) * SCALE, 0.f, (float)(TAB_N - 1));
                f32x2 v = vclamp((lbv - TAB_LO) * SCALE, 0.f, (float)(TAB_N - 1));
                int ia0 = (int)u.x; ia0 = ia0 > TAB_N - 2 ? TAB_N - 2 : ia0;
                int ia1 = (int)u.y; ia1 = ia1 > TAB_N - 2 ? TAB_N - 2 : ia1;
                int ib0 = (int)v.x; ib0 = ib0 > TAB_N - 2 ? TAB_N - 2 : ib0;
                int ib1 = (int)v.y; ib1 = ib1 > TAB_N - 2 ? TAB_N - 2 : ib1;
                f32x2 fa = { u.x - (float)ia0, u.y - (float)ia1 };
                f32x2 fb = { v.x - (float)ib0, v.y - (float)ib1 };
                int o0 = (ia0 * TAB_STRIDE + ib0) * 2;
                int o1 = (ia1 * TAB_STRIDE + ib1) * 2;
                f32x2 e0r0 = *(const f32x2*)&sTab[o0];
                f32x2 e0r1 = *(const f32x2*)&sTab[o0 + TAB_STRIDE * 2];
                f32x2 e1r0 = *(const f32x2*)&sTab[o1];
                f32x2 e1r1 = *(const f32x2*)&sTab[o1 + TAB_STRIDE * 2];
                f32x2 m0 = { e0r0.x + fb.x * (e0r0.y - e0r0.x),
                             e1r0.x + fb.y * (e1r0.y - e1r0.x) };
                f32x2 m1 = { e0r1.x + fb.x * (e0r1.y - e0r1.x),
                             e1r1.x + fb.y * (e1r1.y - e1r1.x) };
                f32x2 att = m0 + fa * (m1 - m0);

                bool oob = (mn < TAB_LO) | (mx > TAB_HI);
                if (__builtin_expect(__any(oob), 0)) {
                    f32x2 ex = hardkuma_slow(la, lbv);
                    if (oob) att = ex;
                }

                out[((size_t)bidx * 2048 + t) * 2048 + s] = att.x;
                out[((size_t)bidx * 2048 + t + 1) * 2048 + s] = att.y;
            }
        }
    }
}

// ---------------------------------------------------------------------------
extern "C" void kernel_launch(void* const* d_in, const int* in_sizes, int n_in,
                              void* d_out, int out_size, void* d_ws, size_t ws_size,
                              hipStream_t stream) {
    const float* q    = (const float*)d_in[0];
    const float* k    = (const float*)d_in[1];
    const float* Wa1  = (const float*)d_in[2];
    const float* Wa2  = (const float*)d_in[4];
    const float* Wb1  = (const float*)d_in[6];
    const float* Wb2  = (const float*)d_in[8];
    const float* dist = (const float*)d_in[10];
    float* out = (float*)d_out;

    bf16* wsbf = (bf16*)d_ws;
    bf16* Wa1t = wsbf;                 // 512*256
    bf16* Wa2t = Wa1t + 131072;        // 256*256
    bf16* Wb1t = Wa2t + 65536;
    bf16* Wb2t = Wb1t + 131072;
    bf16* qa   = Wb2t + 65536;         // 8192*256 each
    bf16* ka   = qa + 2097152;
    bf16* qb   = ka + 2097152;
    bf16* kb   = qb + 2097152;
    bf16* tail = kb + 2097152;
    float* tabg = (float*)tail;        // 64*65*2 f32 = 33.3 KB

    // prep (blocks 0..1535) + table gen (blocks 1536..1551), one launch
    prep_weights<<<1552, 256, 0, stream>>>(Wa1, Wa2, Wb1, Wb2,
                                           Wa1t, Wa2t, Wb1t, Wb2t, tabg);

    dim3 g1(128, 1, 4), blk512(512, 1, 1);
    mlp_fused<<<g1, blk512, 0, stream>>>(q, k, Wa1t, Wa2t, Wb1t, Wb2t,
                                         qa, ka, qb, kb);

    dim3 g2(16, 16, 4);
    kuma_attn<<<g2, blk512, 0, stream>>>(qa, ka, qb, kb, dist, tabg, out);
}

// Round 10
// 166.117 us; speedup vs baseline: 1.1191x; 1.0875x over previous
//
#include <hip/hip_runtime.h>
#include <hip/hip_bf16.h>
#include <math.h>

typedef __hip_bfloat16 bf16;
typedef short bf16x8 __attribute__((ext_vector_type(8)));   // 8 bf16 raw (4 VGPRs)
typedef float f32x4 __attribute__((ext_vector_type(4)));
typedef float f32x2 __attribute__((ext_vector_type(2)));

union alignas(16) Pack8 { bf16 h[8]; bf16x8 v; };

// native base-2 transcendentals (v_exp_f32 / v_log_f32 / v_rcp_f32)
#define EXP2F(x) __builtin_amdgcn_exp2f(x)
#define LOG2F(x) __builtin_amdgcn_logf(x)
#define RCPF(x)  __builtin_amdgcn_rcpf(x)

// async global->LDS DMA, 16 B/lane. Dest must be the WAVE-UNIFORM base; HW
// scatters lane l to base + l*16 (guide §5 / m97/m104). Size must be literal.
__device__ __forceinline__ void gload16(const void* g, void* l) {
    __builtin_amdgcn_global_load_lds(
        (const __attribute__((address_space(1))) void*)g,
        (__attribute__((address_space(3))) void*)l, 16, 0, 0);
}

// T2 XOR swizzle for [row][64-short] tiles (128 B row stride): without it a
// b128 fragment read is a 16-way bank conflict (all rows start at bank 0).
// col_shorts ^= (row&7)*8  <=>  byte ^= (row&7)<<4.  Involution; stage side
// pre-swizzles the GLOBAL source col (rule #21: dest stays DMA-linear).
#define SWZ(col, row) ((col) ^ (((row) & 7) * 8))

// Mean-table box: for scores in [TAB_LO, TAB_HI] (a,b in [0.533,1.502]),
// pc >= 0.596 always (corner-verified; pc unimodal in each var), so the
// output is ALWAYS the continuous mean there -> bilinear table lookup.
#define TAB_N   64
#define TAB_LO  (-0.35f)
#define TAB_HI  (1.25f)
#define TAB_STRIDE 65          // f32x2 pairs (T[ib],T[ib+1]), row stride 65

// ---------------------------------------------------------------------------
// f32 mean (Stirling shift-4, R0/R1-validated; err ~3e-5). Table gen only.
// ---------------------------------------------------------------------------
__device__ __forceinline__ float stirl2s(float z) {
    float iz = 1.f / z;
    return (z - 0.5f) * LOG2F(z) - 1.44269504f * z + 1.32574806f
         + iz * (0.12022651f - 0.00400749f * iz * iz);
}
__device__ __forceinline__ float sp4s(float x) {   // x(x+1)(x+2)(x+3)
    return (x * (x + 1.f)) * ((x + 2.f) * (x + 3.f));
}
__device__ float mean_f32(float sa, float sb) {
    float lw = LOG2F(1.f + EXP2F(sa * 1.44269504f));
    float lv = LOG2F(1.f + EXP2F(sb * 1.44269504f));
    lw = fminf(fmaxf(lw, 0.01442695f), 144.269504f);
    lv = fminf(fmaxf(lv, 0.01442695f), 144.269504f);
    float b = 0.69314718f * lv;
    float g = 1.44269504f / lw + 1.f;
    float gb = g + b;
    float lb2 = stirl2s(g + 4.f) + stirl2s(b + 4.f) - stirl2s(gb + 4.f)
              + LOG2F(sp4s(gb) / (sp4s(g) * sp4s(b)));
    float mean = fmaf(1.2f * b, EXP2F(lb2), -0.1f);
    return fminf(fmaxf(mean, 0.f), 1.f);
}

// ---------------------------------------------------------------------------
// Weight transposes f32 -> bf16 AND mean-table generation in ONE dispatch.
// ---------------------------------------------------------------------------
__global__ void prep_weights(const float* __restrict__ Wa1, const float* __restrict__ Wa2,
                             const float* __restrict__ Wb1, const float* __restrict__ Wb2,
                             bf16* __restrict__ oa1, bf16* __restrict__ oa2,
                             bf16* __restrict__ ob1, bf16* __restrict__ ob2,
                             float* __restrict__ tab) {
    if (blockIdx.x >= 1536) {
        int idx = (blockIdx.x - 1536) * 256 + threadIdx.x;
        if (idx >= TAB_N * TAB_N) return;
        int ia = idx >> 6, ib = idx & 63;
        const float step = (TAB_HI - TAB_LO) / (TAB_N - 1);
        float sa  = TAB_LO + ia * step;
        float sb  = TAB_LO + ib * step;
        int ib1 = ib < TAB_N - 1 ? ib + 1 : ib;
        float sb1 = TAB_LO + ib1 * step;
        tab[(ia * TAB_STRIDE + ib) * 2]     = mean_f32(sa, sb);
        tab[(ia * TAB_STRIDE + ib) * 2 + 1] = mean_f32(sa, sb1);
        return;
    }
    int idx = blockIdx.x * 256 + threadIdx.x;   // covers 393216
    if (idx < 131072) {
        int n = idx >> 9, k = idx & 511;
        oa1[idx] = __float2bfloat16(Wa1[k * 256 + n]);
    } else if (idx < 196608) {
        int i = idx - 131072; int n = i >> 8, k = i & 255;
        oa2[i] = __float2bfloat16(Wa2[k * 256 + n]);
    } else if (idx < 327680) {
        int i = idx - 196608; int n = i >> 9, k = i & 511;
        ob1[i] = __float2bfloat16(Wb1[k * 256 + n]);
    } else {
        int i = idx - 327680; int n = i >> 8, k = i & 255;
        ob2[i] = __float2bfloat16(Wb2[k * 256 + n]);
    }
}

// ---------------------------------------------------------------------------
// Fused 2-layer MLP — 512 threads (8 waves of 64x32), BK=64, W tiles via
// global_load_lds DMA into [256][64] with T2 swizzle (pre-swizzled source,
// swizzled reads). X tile reg-staged with swizzled writes. grid (128,1,4).
// ---------------------------------------------------------------------------
__global__ __launch_bounds__(512, 4)
void mlp_fused(const float* __restrict__ q, const float* __restrict__ k,
               const bf16* __restrict__ Wa1t, const bf16* __restrict__ Wa2t,
               const bf16* __restrict__ Wb1t, const bf16* __restrict__ Wb2t,
               bf16* __restrict__ qa, bf16* __restrict__ ka,
               bf16* __restrict__ qb, bf16* __restrict__ kb) {
    const int z = blockIdx.z;
    const float* X  = (z & 1) ? k : q;
    const bf16*  W1 = (z >> 1) ? Wb1t : Wa1t;
    const bf16*  W2 = (z >> 1) ? Wb2t : Wa2t;
    bf16* Y = (z == 0) ? qa : (z == 1) ? ka : (z == 2) ? qb : kb;
    const int m0 = blockIdx.x * 64;

    // [0,32768): lB [256][64] bf16 (DMA-linear, swizzled contents)
    // [32768,66560): lH [64][264] bf16 — lA [64][64] ALIASES its head
    __shared__ alignas(16) char smem[66560];
    short* lB = (short*)smem;
    short* lH = (short*)(smem + 32768);
    short* lA = (short*)(smem + 32768);    // dead before lH is written

    const int tid  = threadIdx.x;
    const int wave = tid >> 6, lane = tid & 63;
    const int wn = wave * 32;                   // 8 waves x 32 cols = 256
    const int quad = lane >> 4, r16 = lane & 15;
    const int srow = lane >> 3;                          // DMA lane row 0..7
    const int scolsw = ((lane & 7) ^ (srow & 7)) * 8;    // pre-swizzled src col
    const int car = tid >> 3,  cac = (tid & 7) * 8;      // lA convert mapping

    // ---- layer 1: K = 512, BK = 64 (8 iters)
    {
        f32x4 acc[4][2] = {};
        for (int kk = 0; kk < 512; kk += 64) {
            {   // X convert-stage: swizzled LDS write (reg-staged path)
                const float* p = X + (size_t)(m0 + car) * 512 + kk + cac;
                Pack8 u;
#pragma unroll
                for (int j = 0; j < 8; j++) u.h[j] = __float2bfloat16(p[j]);
                *(bf16x8*)&lA[car * 64 + SWZ(cac, car)] = u.v;
            }
#pragma unroll
            for (int j = 0; j < 4; j++) {       // W1 rows via DMA, 4/wave
                int row = wave * 32 + j * 8 + srow;
                gload16(W1 + (size_t)row * 512 + kk + scolsw,
                        lB + (wave * 32 + j * 8) * 64);
            }
            __syncthreads();
#pragma unroll
            for (int ks = 0; ks < 2; ks++) {
                int co = ks * 32 + quad * 8;
                bf16x8 af[4], bfr[2];
#pragma unroll
                for (int f = 0; f < 4; f++) {
                    int R = f * 16 + r16;
                    af[f] = *(const bf16x8*)&lA[R * 64 + SWZ(co, R)];
                }
#pragma unroll
                for (int f = 0; f < 2; f++) {
                    int R = wn + f * 16 + r16;
                    bfr[f] = *(const bf16x8*)&lB[R * 64 + SWZ(co, R)];
                }
#pragma unroll
                for (int i = 0; i < 4; i++)
#pragma unroll
                    for (int j = 0; j < 2; j++)
                        acc[i][j] = __builtin_amdgcn_mfma_f32_16x16x32_bf16(
                            af[i], bfr[j], acc[i][j], 0, 0, 0);
            }
            __syncthreads();
        }
        // lA dead; lH takes over the aliased region
#pragma unroll
        for (int i = 0; i < 4; i++)
#pragma unroll
            for (int j = 0; j < 2; j++)
#pragma unroll
                for (int r = 0; r < 4; r++) {
                    float v = acc[i][j][r];
                    v = v > 0.f ? v : 0.f;
                    ((bf16*)lH)[(i * 16 + quad * 4 + r) * 264 + wn + j * 16 + r16] =
                        __float2bfloat16(v);
                }
    }
    __syncthreads();

    // ---- layer 2: K = 256, BK = 64 (4 iters), A from lH, W2 via DMA
    f32x4 acc2[4][2] = {};
    for (int kk = 0; kk < 256; kk += 64) {
#pragma unroll
        for (int j = 0; j < 4; j++) {
            int row = wave * 32 + j * 8 + srow;
            gload16(W2 + (size_t)row * 256 + kk + scolsw,
                    lB + (wave * 32 + j * 8) * 64);
        }
        __syncthreads();
#pragma unroll
        for (int ks = 0; ks < 2; ks++) {
            int cb = ks * 32 + quad * 8;
            bf16x8 af[4], bfr[2];
#pragma unroll
            for (int f = 0; f < 4; f++)
                af[f] = *(const bf16x8*)&lH[(f * 16 + r16) * 264 + kk + cb];
#pragma unroll
            for (int f = 0; f < 2; f++) {
                int R = wn + f * 16 + r16;
                bfr[f] = *(const bf16x8*)&lB[R * 64 + SWZ(cb, R)];
            }
#pragma unroll
            for (int i = 0; i < 4; i++)
#pragma unroll
                for (int j = 0; j < 2; j++)
                    acc2[i][j] = __builtin_amdgcn_mfma_f32_16x16x32_bf16(
                        af[i], bfr[j], acc2[i][j], 0, 0, 0);
        }
        __syncthreads();
    }

#pragma unroll
    for (int i = 0; i < 4; i++) {
        int rbase = m0 + i * 16 + quad * 4;
#pragma unroll
        for (int j = 0; j < 2; j++) {
            int col = wn + j * 16 + r16;
#pragma unroll
            for (int r = 0; r < 4; r++) {
                float v = acc2[i][j][r];
                v = v > 0.f ? v : 0.f;
                Y[(size_t)(rbase + r) * 256 + col] = __float2bfloat16(v);
            }
        }
    }
}

// ---------------------------------------------------------------------------
// Packed f32x2 helpers.
// ---------------------------------------------------------------------------
__device__ __forceinline__ f32x2 vexp2(f32x2 x) {
    f32x2 r; r.x = EXP2F(x.x); r.y = EXP2F(x.y); return r;
}
__device__ __forceinline__ f32x2 vlog2(f32x2 x) {
    f32x2 r; r.x = LOG2F(x.x); r.y = LOG2F(x.y); return r;
}
__device__ __forceinline__ f32x2 vrcp(f32x2 x) {
    f32x2 r; r.x = RCPF(x.x); r.y = RCPF(x.y); return r;
}
__device__ __forceinline__ f32x2 vclamp(f32x2 x, float lo, float hi) {
    f32x2 r;
    r.x = fminf(fmaxf(x.x, lo), hi);
    r.y = fminf(fmaxf(x.y, lo), hi);
    return r;
}

// Exact HardKuma pair (round-1 validated). COLD fallback path only.
__device__ __noinline__ f32x2 hardkuma_slow(f32x2 la, f32x2 lb) {
    const float LOG2E = 1.44269504f;
    f32x2 lw = vlog2(1.f + vexp2(la * LOG2E));
    f32x2 lv = vlog2(1.f + vexp2(lb * LOG2E));
    lw = vclamp(lw, 0.01442695f, 144.269504f);   // a in [0.01,100]
    lv = vclamp(lv, 0.01442695f, 144.269504f);
    f32x2 b = 0.69314718f * lv;

    f32x2 t0a = vexp2(-2.48490665f * lw);        // 12^{-a}
    f32x2 t1a = vexp2(-0.08701138f * lw);        // (12/11)^{-a}
    f32x2 q0 = vexp2(b * vlog2(1.f - t0a));      // 1 - p0
    f32x2 p1 = vexp2(b * vlog2(1.f - t1a));      // P(h=1)
    f32x2 pc = q0 - p1;
    f32x2 p0 = 1.f - q0;

    f32x2 g  = 1.44269504f * vrcp(lw) + 1.f;
    f32x2 gb = g + b;
    f32x2 g2 = g + 2.f, b2 = b + 2.f, gb2 = gb + 2.f;

    f32x2 s = (g + 1.5f) * vlog2(g2) + (b + 1.5f) * vlog2(b2)
            - (gb + 1.5f) * vlog2(gb2);

    const float C1 = 0.12022459f;                // log2e/12
    const float C2 = -0.00400749f;               // -log2e/360
    f32x2 pg  = g2 * b2;
    f32x2 rr3 = vrcp(pg * gb2);
    f32x2 ig  = rr3 * (b2 * gb2);
    f32x2 ib  = rr3 * (g2 * gb2);
    f32x2 igb = rr3 * pg;
    f32x2 corr = ig  * (C1 + C2 * (ig  * ig))
               + ib  * (C1 + C2 * (ib  * ib))
               - igb * (C1 + C2 * (igb * igb));
    s += corr - 1.55964202f;                     // 0.5*log2(2pi) - 2*log2e

    f32x2 ng = g * (g + 1.f), nb = b * (b + 1.f), ngb = gb * (gb + 1.f);
    s += vlog2(ngb * vrcp(ng * nb));

    f32x2 mean = (1.2f * b) * vexp2(s) - 0.1f;
    mean = vclamp(mean, 0.f, 1.f);

    f32x2 att;
    att.x = (pc.x < 0.5f) ? ((p0.x > p1.x) ? 0.f : 1.f) : mean.x;
    att.y = (pc.y < 0.5f) ? ((p0.y > p1.y) ? 0.f : 1.f) : mean.y;
    return att;
}

// ---------------------------------------------------------------------------
// Fused score GEMMs + table epilogue — 512 threads (8 waves of 64x32), BK=64,
// DMA staging with T2 swizzle: pre-swizzled global source col + swizzled
// fragment reads (fixes R9's 16-way read conflict on the 128 B-stride tiles).
// Table aliases the dead tile region for the epilogue. grid (16,16,4).
// ---------------------------------------------------------------------------
__global__ __launch_bounds__(512, 4)
void kuma_attn(const bf16* __restrict__ qa, const bf16* __restrict__ ka,
               const bf16* __restrict__ qb, const bf16* __restrict__ kb,
               const float* __restrict__ dist_emb, const float* __restrict__ tabg,
               float* __restrict__ out) {
    const int bidx = blockIdx.z;
    const int t0 = blockIdx.x * 128;
    const int s0 = blockIdx.y * 128;

    // [0,16384) lQa | [16384,32768) lQb | [32768,49152) lKa | [49152,65536) lKb
    // epilogue: sTab (33280 B) aliases [0,33280);  sDist at [65536,65628)
    __shared__ alignas(16) char smem[65628];
    short* lQa = (short*)smem;
    short* lQb = (short*)(smem + 16384);
    short* lKa = (short*)(smem + 32768);
    short* lKb = (short*)(smem + 49152);
    float* sTab  = (float*)smem;
    float* sDist = (float*)(smem + 65536);

    const int tid = threadIdx.x;
    if (tid < 23) sDist[tid] = dist_emb[tid];

    const int wave = tid >> 6, lane = tid & 63;
    const int wm = (wave >> 2) * 64;             // 2 wave-rows of 64
    const int wn = (wave & 3) * 32;              // 4 wave-cols of 32
    const int quad = lane >> 4, r16 = lane & 15;
    const size_t base = (size_t)bidx * 2048 * 256;

    const int srow = lane >> 3;
    const int scolsw = ((lane & 7) ^ (srow & 7)) * 8;   // pre-swizzled src col

    f32x4 accA[4][2] = {};
    f32x4 accB[4][2] = {};

    for (int kk = 0; kk < 256; kk += 64) {
#pragma unroll
        for (int j = 0; j < 2; j++) {            // 8 DMA per wave per iter
            int row = wave * 16 + j * 8 + srow;
            size_t gq = base + (size_t)(t0 + row) * 256 + kk + scolsw;
            size_t gk = base + (size_t)(s0 + row) * 256 + kk + scolsw;
            int ld = (wave * 16 + j * 8) * 64;   // shorts (wave-uniform)
            gload16(qa + gq, lQa + ld);
            gload16(qb + gq, lQb + ld);
            gload16(ka + gk, lKa + ld);
            gload16(kb + gk, lKb + ld);
        }
        __syncthreads();                          // drains DMA (vmcnt) + WAR
#pragma unroll
        for (int ks = 0; ks < 2; ks++) {
            int co = ks * 32 + quad * 8;
            bf16x8 aA[4], aB[4], bA[2], bB[2];
#pragma unroll
            for (int f = 0; f < 4; f++) {
                int R = wm + f * 16 + r16;
                int ar = R * 64 + SWZ(co, R);
                aA[f] = *(const bf16x8*)&lQa[ar];
                aB[f] = *(const bf16x8*)&lQb[ar];
            }
#pragma unroll
            for (int f = 0; f < 2; f++) {
                int R = wn + f * 16 + r16;
                int br = R * 64 + SWZ(co, R);
                bA[f] = *(const bf16x8*)&lKa[br];
                bB[f] = *(const bf16x8*)&lKb[br];
            }
#pragma unroll
            for (int i = 0; i < 4; i++)
#pragma unroll
                for (int j = 0; j < 2; j++) {
                    accA[i][j] = __builtin_amdgcn_mfma_f32_16x16x32_bf16(
                        aA[i], bA[j], accA[i][j], 0, 0, 0);
                    accB[i][j] = __builtin_amdgcn_mfma_f32_16x16x32_bf16(
                        aB[i], bB[j], accB[i][j], 0, 0, 0);
                }
        }
        __syncthreads();
    }

    // Load the mean table into the now-dead tile region, then sync once.
    for (int i = tid; i < (TAB_N * TAB_STRIDE * 2) / 4; i += 512)
        ((f32x4*)sTab)[i] = ((const f32x4*)tabg)[i];
    __syncthreads();

    // Epilogue: bilinear mean-table lookup (pairs via ds_read_b64);
    // __any-guarded exact fallback for out-of-box lanes.
    const float SCALE = (TAB_N - 1) / (TAB_HI - TAB_LO);   // 39.375
#pragma unroll
    for (int i = 0; i < 4; i++) {
#pragma unroll
        for (int j = 0; j < 2; j++) {
            int s = s0 + wn + j * 16 + r16;
#pragma unroll
            for (int rr = 0; rr < 2; rr++) {
                int t = t0 + wm + i * 16 + quad * 4 + rr * 2;
                int d0 = s - t;
                int d1 = d0 - 1;
                d0 = d0 < -11 ? -11 : (d0 > 11 ? 11 : d0);
                d1 = d1 < -11 ? -11 : (d1 > 11 ? 11 : d1);
                float rd0 = sDist[d0 + 11];
                float rd1 = sDist[d1 + 11];
                f32x2 la  = { accA[i][j][rr * 2] + rd0, accA[i][j][rr * 2 + 1] + rd1 };
                f32x2 lbv = { accB[i][j][rr * 2] + rd0, accB[i][j][rr * 2 + 1] + rd1 };

                float mn = fminf(fminf(la.x, la.y), fminf(lbv.x, lbv.y));
                float mx = fmaxf(fmaxf(la.x, la.y), fmaxf(lbv.x, lbv.y));

                f32x2 u = vclamp((la  - TAB_LO) * SCALE, 0.f, (float)(TAB_N - 1));
                f32x2 v = vclamp((lbv - TAB_LO) * SCALE, 0.f, (float)(TAB_N - 1));
                int ia0 = (int)u.x; ia0 = ia0 > TAB_N - 2 ? TAB_N - 2 : ia0;
                int ia1 = (int)u.y; ia1 = ia1 > TAB_N - 2 ? TAB_N - 2 : ia1;
                int ib0 = (int)v.x; ib0 = ib0 > TAB_N - 2 ? TAB_N - 2 : ib0;
                int ib1 = (int)v.y; ib1 = ib1 > TAB_N - 2 ? TAB_N - 2 : ib1;
                f32x2 fa = { u.x - (float)ia0, u.y - (float)ia1 };
                f32x2 fb = { v.x - (float)ib0, v.y - (float)ib1 };
                int o0 = (ia0 * TAB_STRIDE + ib0) * 2;
                int o1 = (ia1 * TAB_STRIDE + ib1) * 2;
                f32x2 e0r0 = *(const f32x2*)&sTab[o0];
                f32x2 e0r1 = *(const f32x2*)&sTab[o0 + TAB_STRIDE * 2];
                f32x2 e1r0 = *(const f32x2*)&sTab[o1];
                f32x2 e1r1 = *(const f32x2*)&sTab[o1 + TAB_STRIDE * 2];
                f32x2 m0 = { e0r0.x + fb.x * (e0r0.y - e0r0.x),
                             e1r0.x + fb.y * (e1r0.y - e1r0.x) };
                f32x2 m1 = { e0r1.x + fb.x * (e0r1.y - e0r1.x),
                             e1r1.x + fb.y * (e1r1.y - e1r1.x) };
                f32x2 att = m0 + fa * (m1 - m0);

                bool oob = (mn < TAB_LO) | (mx > TAB_HI);
                if (__builtin_expect(__any(oob), 0)) {
                    f32x2 ex = hardkuma_slow(la, lbv);
                    if (oob) att = ex;
                }

                out[((size_t)bidx * 2048 + t) * 2048 + s] = att.x;
                out[((size_t)bidx * 2048 + t + 1) * 2048 + s] = att.y;
            }
        }
    }
}

// ---------------------------------------------------------------------------
extern "C" void kernel_launch(void* const* d_in, const int* in_sizes, int n_in,
                              void* d_out, int out_size, void* d_ws, size_t ws_size,
                              hipStream_t stream) {
    const float* q    = (const float*)d_in[0];
    const float* k    = (const float*)d_in[1];
    const float* Wa1  = (const float*)d_in[2];
    const float* Wa2  = (const float*)d_in[4];
    const float* Wb1  = (const float*)d_in[6];
    const float* Wb2  = (const float*)d_in[8];
    const float* dist = (const float*)d_in[10];
    float* out = (float*)d_out;

    bf16* wsbf = (bf16*)d_ws;
    bf16* Wa1t = wsbf;                 // 512*256
    bf16* Wa2t = Wa1t + 131072;        // 256*256
    bf16* Wb1t = Wa2t + 65536;
    bf16* Wb2t = Wb1t + 131072;
    bf16* qa   = Wb2t + 65536;         // 8192*256 each
    bf16* ka   = qa + 2097152;
    bf16* qb   = ka + 2097152;
    bf16* kb   = qb + 2097152;
    bf16* tail = kb + 2097152;
    float* tabg = (float*)tail;        // 64*65*2 f32 = 33.3 KB

    // prep (blocks 0..1535) + table gen (blocks 1536..1551), one launch
    prep_weights<<<1552, 256, 0, stream>>>(Wa1, Wa2, Wb1, Wb2,
                                           Wa1t, Wa2t, Wb1t, Wb2t, tabg);

    dim3 g1(128, 1, 4), blk512(512, 1, 1);
    mlp_fused<<<g1, blk512, 0, stream>>>(q, k, Wa1t, Wa2t, Wb1t, Wb2t,
                                         qa, ka, qb, kb);

    dim3 g2(16, 16, 4);
    kuma_attn<<<g2, blk512, 0, stream>>>(qa, ka, qb, kb, dist, tabg, out);
}